// Round 1
// baseline (50.622 us; speedup 1.0000x reference)
//
#include <hip/hip_runtime.h>

#define BB 2
#define NN 512
#define DD 64
#define LN_EPS 1e-5f
#define NEG_SLOPE 0.01f

__device__ __forceinline__ float wave_reduce_sum(float v) {
    #pragma unroll
    for (int off = 32; off >= 1; off >>= 1)
        v += __shfl_xor(v, off, 64);
    return v;
}

__device__ __forceinline__ float wave_reduce_max(float v) {
    #pragma unroll
    for (int off = 32; off >= 1; off >>= 1)
        v = fmaxf(v, __shfl_xor(v, off, 64));
    return v;
}

// One 64-lane wave per row. Rows 0..B*N-1: ua rows -> sq, sk.
// Rows B*N..B*N+B-1: iid rows -> c[b] = siid + b_att.
__global__ __launch_bounds__(64) void precompute_kernel(
    const float* __restrict__ ua,
    const float* __restrict__ iid,
    const float* __restrict__ ln_g,
    const float* __restrict__ ln_b,
    const float* __restrict__ w_att,
    const float* __restrict__ b_att,
    float* __restrict__ sq,
    float* __restrict__ sk,
    float* __restrict__ cb) {
    const int bid = blockIdx.x;
    const int lane = threadIdx.x;

    const float g = ln_g[lane];
    const float bet = ln_b[lane];

    if (bid < BB * NN) {
        float x = ua[bid * DD + lane];
        float m = wave_reduce_sum(x) * (1.0f / DD);
        float xc = x - m;
        float var = wave_reduce_sum(xc * xc) * (1.0f / DD);
        float r = rsqrtf(var + LN_EPS);
        float w = xc * r * g + bet;
        float s1 = wave_reduce_sum(w * w_att[lane]);
        float s2 = wave_reduce_sum(w * w_att[DD + lane]);
        if (lane == 0) {
            sq[bid] = s1;
            sk[bid] = s2;
        }
    } else {
        int b = bid - BB * NN;
        float x = iid[b * DD + lane];
        float m = wave_reduce_sum(x) * (1.0f / DD);
        float xc = x - m;
        float var = wave_reduce_sum(xc * xc) * (1.0f / DD);
        float r = rsqrtf(var + LN_EPS);
        float w = xc * r * g + bet;
        float s3 = wave_reduce_sum(w * w_att[2 * DD + lane]);
        if (lane == 0) {
            cb[b] = s3 + b_att[0];
        }
    }
}

// One block per (b, i) row. Softmax over j (512), then stream both outputs.
__global__ __launch_bounds__(256) void write_kernel(
    const float* __restrict__ ua,
    const float* __restrict__ sq,
    const float* __restrict__ sk,
    const float* __restrict__ cb,
    float* __restrict__ out0,   // alphas broadcast [B,N,N,D]
    float* __restrict__ out1) { // value = q*k      [B,N,N,D]
    __shared__ float alpha_sh[NN];
    __shared__ float red_mx[4];
    __shared__ float red_sm[4];

    const int bid = blockIdx.x;       // b*N + i
    const int b = bid >> 9;           // / NN
    const int tid = threadIdx.x;

    const float sqi = sq[bid];
    const float c = cb[b];

    // scores for this thread's two j's
    float s0 = sqi + sk[b * NN + tid] + c;
    float s1 = sqi + sk[b * NN + tid + 256] + c;
    s0 = (s0 >= 0.0f) ? s0 : NEG_SLOPE * s0;
    s1 = (s1 >= 0.0f) ? s1 : NEG_SLOPE * s1;

    // block max
    float mx = fmaxf(s0, s1);
    mx = wave_reduce_max(mx);
    const int wid = tid >> 6;
    if ((tid & 63) == 0) red_mx[wid] = mx;
    __syncthreads();
    mx = fmaxf(fmaxf(red_mx[0], red_mx[1]), fmaxf(red_mx[2], red_mx[3]));

    // block sum of exp
    float e0 = expf(s0 - mx);
    float e1 = expf(s1 - mx);
    float sm = wave_reduce_sum(e0 + e1);
    if ((tid & 63) == 0) red_sm[wid] = sm;
    __syncthreads();
    sm = red_sm[0] + red_sm[1] + red_sm[2] + red_sm[3];
    const float inv = 1.0f / sm;

    alpha_sh[tid] = e0 * inv;
    alpha_sh[tid + 256] = e1 * inv;
    __syncthreads();

    // write phase: per-thread fixed d4 = tid&15, j walks jbase + k*16
    const int d4 = tid & 15;
    const int jbase = tid >> 4;

    const float4* __restrict__ uaB = (const float4*)(ua + (size_t)b * NN * DD);
    const float4 ui = uaB[((size_t)(bid & (NN - 1))) * 16 + d4];

    float4* __restrict__ o0 = (float4*)(out0 + (size_t)bid * NN * DD);
    float4* __restrict__ o1 = (float4*)(out1 + (size_t)bid * NN * DD);

    #pragma unroll 4
    for (int k = 0; k < 32; ++k) {
        const int j = jbase + k * 16;
        const float a = alpha_sh[j];
        const float4 uj = uaB[j * 16 + d4];
        float4 av;
        av.x = a; av.y = a; av.z = a; av.w = a;
        float4 val;
        val.x = ui.x * uj.x;
        val.y = ui.y * uj.y;
        val.z = ui.z * uj.z;
        val.w = ui.w * uj.w;
        o0[j * 16 + d4] = av;
        o1[j * 16 + d4] = val;
    }
}

extern "C" void kernel_launch(void* const* d_in, const int* in_sizes, int n_in,
                              void* d_out, int out_size, void* d_ws, size_t ws_size,
                              hipStream_t stream) {
    const float* ua    = (const float*)d_in[0];
    const float* iid   = (const float*)d_in[1];
    const float* ln_g  = (const float*)d_in[2];
    const float* ln_b  = (const float*)d_in[3];
    const float* w_att = (const float*)d_in[4];
    const float* b_att = (const float*)d_in[5];

    float* out0 = (float*)d_out;                                // alphas [B,N,N,D]
    float* out1 = out0 + (size_t)BB * NN * NN * DD;             // value  [B,N,N,D]

    float* sq = (float*)d_ws;          // B*N
    float* sk = sq + BB * NN;          // B*N
    float* cb = sk + BB * NN;          // B

    precompute_kernel<<<BB * NN + BB, 64, 0, stream>>>(ua, iid, ln_g, ln_b,
                                                       w_att, b_att, sq, sk, cb);
    write_kernel<<<BB * NN, 256, 0, stream>>>(ua, sq, sk, cb, out0, out1);
}